// Round 5
// baseline (86.623 us; speedup 1.0000x reference)
//
#include <hip/hip_runtime.h>
#include <hip/hip_bf16.h>
#include <cmath>
#include <cstdint>

#define Bsz   4096
#define INsz  512
#define OUTsz 512
#define NRING 16
#define KTOT  8704          /* IN*(NR+1): residual folded in as 17th slot */
#define SPLITK 4
#define NPH   34            /* 2 i-halves x 17 rings, K=64 each */

using short8 = __attribute__((ext_vector_type(8))) short;
using f32x4  = __attribute__((ext_vector_type(4))) float;

struct RC {
  float Cr[NRING];    // cos(2*pi*rev0_r)
  float Snr[NRING];   // -sin(2*pi*rev0_r)
  float K2, SQ, pad0, pad1;  // h=K2*xc*rcp(wl); A' = rcp(cph + SQ)
};

__device__ __forceinline__ unsigned short f2bf(float f) {
  __hip_bfloat16 h = __float2bfloat16(f);               // native cvt (RNE)
  return *reinterpret_cast<unsigned short*>(&h);
}
__device__ __forceinline__ float fastrcp(float x) {
#if __has_builtin(__builtin_amdgcn_rcpf)
  return __builtin_amdgcn_rcpf(x);
#else
  return 1.0f / x;
#endif
}
__device__ __forceinline__ float fastfract(float x) {
#if __has_builtin(__builtin_amdgcn_fractf)
  return __builtin_amdgcn_fractf(x);
#else
  return x - floorf(x);
#endif
}
__device__ __forceinline__ float cos2pi(float fr) {
#if __has_builtin(__builtin_amdgcn_cosf)
  return __builtin_amdgcn_cosf(fr);
#else
  return __cosf(fr * 6.28318530717958647692f);
#endif
}
__device__ __forceinline__ float sin2pi(float fr) {
#if __has_builtin(__builtin_amdgcn_sinf)
  return __builtin_amdgcn_sinf(fr);
#else
  return __sinf(fr * 6.28318530717958647692f);
#endif
}

__device__ __forceinline__ void gl_lds16(const void* g, void* l) {
  __builtin_amdgcn_global_load_lds(
      (const __attribute__((address_space(1))) void*)g,
      (__attribute__((address_space(3))) void*)l, 16, 0, 0);
}

// ---- pack B'^T: [OUT][KTOT] bf16, k = n*512 + i; also bias[o] = sum coeffs ----
__global__ __launch_bounds__(512) void pack_b_kernel(
    const float* __restrict__ coeffs, const float* __restrict__ bw,
    unsigned short* __restrict__ Bt, float* __restrict__ bias, float PQ) {
  __shared__ float red[8];
  const int o = blockIdx.x;        // 512 blocks
  const int i = threadIdx.x;       // 512 threads
  const float* cp = coeffs + ((size_t)i * OUTsz + o) * NRING;  // 64B contiguous
  unsigned short* row = Bt + (size_t)o * KTOT + i;
  float s = 0.0f;
#pragma unroll
  for (int j = 0; j < 4; ++j) {
    f32x4 v = *reinterpret_cast<const f32x4*>(cp + j * 4);
#pragma unroll
    for (int e = 0; e < 4; ++e) {
      const int n = j * 4 + e;
      s += v[e];
      row[(size_t)n * INsz] = f2bf(PQ * v[e]);
    }
  }
  row[(size_t)NRING * INsz] = f2bf(bw[(size_t)i * OUTsz + o]);  // residual unscaled
#pragma unroll
  for (int off = 32; off > 0; off >>= 1) s += __shfl_down(s, off);
  const int w = i >> 6;
  if ((i & 63) == 0) red[w] = s;
  __syncthreads();
  if (i == 0) {
    float t = 0.0f;
#pragma unroll
    for (int k = 0; k < 8; ++k) t += red[k];
    bias[o] = t;
  }
}

// ---- fused basis-gen + split-K bf16 MFMA GEMM, BM=128 x BN=128, 8 waves ----
// grid 512 = 2 blocks/CU (80KB LDS). bid: combo=bid&15 -> (cb,ks), rb=bid>>4.
// LDS: As[2][128][64] (16KB x2) + Bs[3][128][64] (16KB x3) = 80KB dynamic.
// Schedule: 2-deep B prefetch, counted vmcnt(2), 1 barrier/phase.
__global__ __launch_bounds__(512, 4) void gemm_fused_kernel(
    const float* __restrict__ x, const unsigned short* __restrict__ Bt,
    float* __restrict__ part, RC rc) {
  extern __shared__ char smem[];
  char* smA = smem;            // 2 x 16384
  char* smB = smem + 32768;    // 3 x 16384
  const int tid  = threadIdx.x;
  const int lane = tid & 63;
  const int w    = tid >> 6;
  const int bid  = blockIdx.x;
  const int combo = bid & 15;        // same combo -> same XCD (bid%8 fixed)
  const int rb   = bid >> 4;         // 0..31
  const int cb   = combo & 3, ks = combo >> 2;
  const int brow = rb * 128, bcol = cb * 128;

  // --- A-gen ownership: row r (0..127), i-quarter q4 (16 i's per thread) ---
  const int r  = tid & 127;
  const int q4 = tid >> 7;           // 0..3
  const int wb0 = r * 128 + (((q4 * 2 + 0) ^ (r & 7)) * 16);
  const int wb1 = r * 128 + (((q4 * 2 + 1) ^ (r & 7)) * 16);

  // --- B staging: pre-swizzled per-lane global source, linear LDS dest ---
  const int cg = (lane & 7) ^ ((lane >> 3) & 7);
  const unsigned short* gb0 = Bt + (size_t)(bcol + w * 8 + (lane >> 3)) * KTOT + cg * 8;

  // --- fragment read geometry: 8 waves = 2M x 4N, wave tile 64x32 ---
  const int wr = w >> 2, wc = w & 3;
  const int l7 = lane & 7;
  const int rowA = wr * 64 + (lane & 15);
  const int rowB = wc * 32 + (lane & 15);

  // --- prologue: ALL x loads + trig(is=0); is=1 floats kept for p==16 ---
  float xf0[16], xf1[16], cth[16], sth[16];
  short8 xbf0a, xbf0b, xbf1a, xbf1b;   // raw x as bf16 (residual ring)
  const float* gx = x + (size_t)(brow + r) * INsz + ks * 128 + q4 * 16;
#pragma unroll
  for (int j = 0; j < 4; ++j) {
    f32x4 v0 = *reinterpret_cast<const f32x4*>(gx + j * 4);
    f32x4 v1 = *reinterpret_cast<const f32x4*>(gx + 64 + j * 4);
#pragma unroll
    for (int e = 0; e < 4; ++e) { xf0[j * 4 + e] = v0[e]; xf1[j * 4 + e] = v1[e]; }
  }
#pragma unroll
  for (int c = 0; c < 8; ++c) {
    xbf0a[c] = (short)f2bf(xf0[c]);     xbf0b[c] = (short)f2bf(xf0[c + 8]);
    xbf1a[c] = (short)f2bf(xf1[c]);     xbf1b[c] = (short)f2bf(xf1[c + 8]);
  }
  auto TRIG = [&](const float* xf) {
#pragma unroll
    for (int c = 0; c < 16; ++c) {
      float xc = fminf(fmaxf(xf[c], -1.0f), 1.0f);
      float wl = __builtin_fmaf(xc, 4.0e-9f, 1550.0e-9f);
      float hh = rc.K2 * xc * fastrcp(wl);
      float fr = fastfract(hh);
      cth[c] = cos2pi(fr);
      sth[c] = sin2pi(fr);
    }
  };
  TRIG(xf0);

  auto STAGE = [&](int p) {   // 2 gl_lds (2 x 64 rows) for B-tile of phase p
    const int is = (p >= 17) ? 1 : 0, n = p - 17 * is;
    const size_t koff = (size_t)(n * 512 + ks * 128 + is * 64);
    char* ldst = smB + (p % 3) * 16384 + w * 1024;
    const unsigned short* src = gb0 + koff;
    gl_lds16(src, ldst);
    gl_lds16(src + (size_t)64 * KTOT, ldst + 8192);
  };
  auto GENA = [&](int p) {    // generate A-tile of phase p into As[p&1]
    const int is = (p >= 17) ? 1 : 0, n = p - 17 * is;
    char* dst = smA + (p & 1) * 16384;
    if (n < NRING) {
      const float Crn = rc.Cr[n], Snn = rc.Snr[n];
#pragma unroll
      for (int g = 0; g < 2; ++g) {
        short8 wv;
#pragma unroll
        for (int e = 0; e < 8; ++e) {
          float cph = __builtin_fmaf(cth[g * 8 + e], Crn, sth[g * 8 + e] * Snn);
          wv[e] = (short)f2bf(fastrcp(cph + rc.SQ));
        }
        *reinterpret_cast<short8*>(dst + (g ? wb1 : wb0)) = wv;
      }
    } else {                  // residual ring: raw (unclipped) x, pre-packed
      *reinterpret_cast<short8*>(dst + wb0) = is ? xbf1a : xbf0a;
      *reinterpret_cast<short8*>(dst + wb1) = is ? xbf1b : xbf0b;
    }
  };

  f32x4 acc[4][2];
#pragma unroll
  for (int m = 0; m < 4; ++m)
#pragma unroll
    for (int q = 0; q < 2; ++q) acc[m][q] = (f32x4){0.f, 0.f, 0.f, 0.f};

  STAGE(0); STAGE(1);
  GENA(0);
  asm volatile("s_waitcnt vmcnt(2) lgkmcnt(0)" ::: "memory");
  __builtin_amdgcn_s_barrier();
  __builtin_amdgcn_sched_barrier(0);

#pragma unroll
  for (int p = 0; p < NPH; ++p) {
    if (p + 2 < NPH) STAGE(p + 2);
    if (p == 16) TRIG(xf1);           // refresh trig for is=1 (regs only)
    const char* bA = smA + (p & 1) * 16384;
    const char* bB = smB + (p % 3) * 16384;
    short8 af[2][4], bfr[2][2];
#pragma unroll
    for (int kk = 0; kk < 2; ++kk) {
      const int oct = (((lane >> 4) + kk * 4) ^ l7) * 16;
#pragma unroll
      for (int m = 0; m < 4; ++m)
        af[kk][m] = *reinterpret_cast<const short8*>(bA + (rowA + m * 16) * 128 + oct);
#pragma unroll
      for (int q = 0; q < 2; ++q)
        bfr[kk][q] = *reinterpret_cast<const short8*>(bB + (rowB + q * 16) * 128 + oct);
    }
    if (p + 1 < NPH) GENA(p + 1);
    __builtin_amdgcn_s_setprio(1);
#pragma unroll
    for (int kk = 0; kk < 2; ++kk)
#pragma unroll
      for (int m = 0; m < 4; ++m)
#pragma unroll
        for (int q = 0; q < 2; ++q)
          acc[m][q] = __builtin_amdgcn_mfma_f32_16x16x32_bf16(af[kk][m], bfr[kk][q], acc[m][q], 0, 0, 0);
    __builtin_amdgcn_s_setprio(0);
    if (p + 1 < NPH) {
      if (p + 2 < NPH) {
        asm volatile("s_waitcnt vmcnt(2) lgkmcnt(0)" ::: "memory");  // B(p+1) done, B(p+2) in flight
      } else {
        asm volatile("s_waitcnt vmcnt(0) lgkmcnt(0)" ::: "memory");  // drain for last phase
      }
      __builtin_amdgcn_s_barrier();
      __builtin_amdgcn_sched_barrier(0);
    }
  }

  float* po = part + (size_t)ks * ((size_t)Bsz * OUTsz);
  const int r0 = brow + wr * 64 + ((lane >> 4) * 4);
  const int c0 = bcol + wc * 32 + (lane & 15);
#pragma unroll
  for (int m = 0; m < 4; ++m)
#pragma unroll
    for (int q = 0; q < 2; ++q)
#pragma unroll
      for (int e = 0; e < 4; ++e)
        po[(size_t)(r0 + m * 16 + e) * OUTsz + (c0 + q * 16)] = acc[m][q][e];
}

// ---- reduce 4 split-K partials + bias + kl ----
__global__ __launch_bounds__(256) void reduce_kernel(
    const f32x4* __restrict__ part, const f32x4* __restrict__ bias,
    float* __restrict__ out) {
  const size_t idx = (size_t)blockIdx.x * 256 + threadIdx.x;
  const size_t stride = (size_t)Bsz * OUTsz / 4;
  f32x4 v = part[idx] + part[idx + stride] + part[idx + 2 * stride] + part[idx + 3 * stride];
  v = v + bias[idx & 127];
  reinterpret_cast<f32x4*>(out)[idx] = v;
  if (idx == 0) out[(size_t)Bsz * OUTsz] = 0.0f;   // kl
}

extern "C" void kernel_launch(void* const* d_in, const int* in_sizes, int n_in,
                              void* d_out, int out_size, void* d_ws, size_t ws_size,
                              hipStream_t stream) {
  const float* x      = (const float*)d_in[0];
  const float* coeffs = (const float*)d_in[1];
  const float* bw     = (const float*)d_in[2];
  float* out = (float*)d_out;

  unsigned short* Bt = (unsigned short*)d_ws;                              // 8,912,896 B
  float* part = (float*)((char*)d_ws + (size_t)OUTsz * KTOT * 2);          // 134,217,728 B
  float* bias = (float*)((char*)d_ws + (size_t)OUTsz * KTOT * 2
                                     + (size_t)SPLITK * Bsz * OUTsz * 4);  // 2048 B

  RC rc;
  float PQ;
  {
    const double PI  = 3.14159265358979323846;
    const double Lc  = 2.0 * PI * 30.0e-6;
    const double WL0 = 1550.0e-9;
    const double NG  = 4.2;
    const double Aamp = pow(10.0, -3.0 * (Lc * 100.0) / 20.0);
    const double Rt2  = 0.8;
    const double Rt   = sqrt(Rt2);
    for (int rr = 0; rr < NRING; ++rr) {
      double off  = -PI + rr * (2.0 * PI / 15.0);
      double neff = 2.34 + off * WL0 / (2.0 * PI * Lc);
      double rev0 = (Lc / WL0) * neff;
      rc.Cr[rr]  = (float)cos(2.0 * PI * rev0);
      rc.Snr[rr] = (float)(-sin(2.0 * PI * rev0));
    }
    const double qn = -2.0 * Rt * Aamp;
    const double s  = 1.0 + Rt2 * Aamp * Aamp;
    const double P  = -(1.0 - Aamp * Aamp) * (1.0 - Rt2);
    rc.K2 = (float)(-4.0e-9 * Lc * NG / WL0);
    rc.SQ = (float)(s / qn);
    rc.pad0 = rc.pad1 = 0.f;
    PQ = (float)(P / qn);
  }

  hipFuncSetAttribute(reinterpret_cast<const void*>(gemm_fused_kernel),
                      hipFuncAttributeMaxDynamicSharedMemorySize, 81920);

  hipLaunchKernelGGL(pack_b_kernel, dim3(OUTsz), dim3(512), 0, stream,
                     coeffs, bw, Bt, bias, PQ);
  hipLaunchKernelGGL(gemm_fused_kernel, dim3(512), dim3(512), 81920, stream,
                     x, Bt, part, rc);
  hipLaunchKernelGGL(reduce_kernel, dim3((Bsz * OUTsz / 4) / 256), dim3(256), 0, stream,
                     (const f32x4*)part, (const f32x4*)bias, out);
}

// Round 6
// 66.924 us; speedup vs baseline: 1.2943x; 1.2943x over previous
//
#include <hip/hip_runtime.h>
#include <hip/hip_bf16.h>
#include <cmath>
#include <cstdint>

#define Bsz   4096
#define INsz  512
#define OUTsz 512
#define NRING 16
#define KTOT  8704          /* IN*(NR+1): residual folded in as 17th slot */
#define SPLITK 4
#define NPH   34            /* 2 i-halves x 17 rings, K=64 each */

using short8 = __attribute__((ext_vector_type(8))) short;
using f32x4  = __attribute__((ext_vector_type(4))) float;

struct RC {
  float Cr[NRING];    // cos(2*pi*rev0_r)
  float Snr[NRING];   // -sin(2*pi*rev0_r)
  float K2, SQ, pad0, pad1;  // h=K2*xc*rcp(wl); A' = rcp(cph + SQ)
};

__device__ __forceinline__ unsigned short f2bf(float f) {
  __hip_bfloat16 h = __float2bfloat16(f);               // native cvt (RNE)
  return *reinterpret_cast<unsigned short*>(&h);
}
__device__ __forceinline__ float fastrcp(float x) {
#if __has_builtin(__builtin_amdgcn_rcpf)
  return __builtin_amdgcn_rcpf(x);
#else
  return 1.0f / x;
#endif
}
__device__ __forceinline__ float fastfract(float x) {
#if __has_builtin(__builtin_amdgcn_fractf)
  return __builtin_amdgcn_fractf(x);
#else
  return x - floorf(x);
#endif
}
__device__ __forceinline__ float cos2pi(float fr) {
#if __has_builtin(__builtin_amdgcn_cosf)
  return __builtin_amdgcn_cosf(fr);
#else
  return __cosf(fr * 6.28318530717958647692f);
#endif
}
__device__ __forceinline__ float sin2pi(float fr) {
#if __has_builtin(__builtin_amdgcn_sinf)
  return __builtin_amdgcn_sinf(fr);
#else
  return __sinf(fr * 6.28318530717958647692f);
#endif
}

__device__ __forceinline__ void gl_lds16(const void* g, void* l) {
  __builtin_amdgcn_global_load_lds(
      (const __attribute__((address_space(1))) void*)g,
      (__attribute__((address_space(3))) void*)l, 16, 0, 0);
}

// ---- pack B'^T: [OUT][KTOT] bf16, k = n*512 + i; also bias[o] = sum coeffs ----
__global__ __launch_bounds__(512) void pack_b_kernel(
    const float* __restrict__ coeffs, const float* __restrict__ bw,
    unsigned short* __restrict__ Bt, float* __restrict__ bias, float PQ) {
  __shared__ float red[8];
  const int o = blockIdx.x;        // 512 blocks
  const int i = threadIdx.x;       // 512 threads
  const float* cp = coeffs + ((size_t)i * OUTsz + o) * NRING;  // 64B contiguous
  unsigned short* row = Bt + (size_t)o * KTOT + i;
  float s = 0.0f;
#pragma unroll
  for (int j = 0; j < 4; ++j) {
    f32x4 v = *reinterpret_cast<const f32x4*>(cp + j * 4);
#pragma unroll
    for (int e = 0; e < 4; ++e) {
      const int n = j * 4 + e;
      s += v[e];
      row[(size_t)n * INsz] = f2bf(PQ * v[e]);
    }
  }
  row[(size_t)NRING * INsz] = f2bf(bw[(size_t)i * OUTsz + o]);  // residual unscaled
#pragma unroll
  for (int off = 32; off > 0; off >>= 1) s += __shfl_down(s, off);
  const int w = i >> 6;
  if ((i & 63) == 0) red[w] = s;
  __syncthreads();
  if (i == 0) {
    float t = 0.0f;
#pragma unroll
    for (int k = 0; k < 8; ++k) t += red[k];
    bias[o] = t;
  }
}

// ---- fused basis-gen + split-K bf16 MFMA GEMM, BM=128 x BN=256, 8 waves ----
// grid 256 = 1 block/CU (128KB LDS). m201-style sub-phases: per K=64 phase,
// two {reads || stage/gen -> barrier -> lgkm0 -> 16 MFMA -> barrier} subs.
// Counted vmcnt(4) once per phase (STAGE(p+2) stays in flight).
__global__ __launch_bounds__(512) void gemm_fused_kernel(
    const float* __restrict__ x, const unsigned short* __restrict__ Bt,
    float* __restrict__ part, RC rc) {
  extern __shared__ char smem[];
  char* smA = smem;            // 2 x 16384
  char* smB = smem + 32768;    // 3 x 32768
  const int tid  = threadIdx.x;
  const int lane = tid & 63;
  const int w    = tid >> 6;
  const int bid  = blockIdx.x;
  const int cbks = bid & 7;          // same (cb,ks) -> same XCD: Bt slice L2-resident
  const int rb   = bid >> 3;         // 0..31
  const int cb   = cbks & 1, ks = cbks >> 1;
  const int brow = rb * 128, bcol = cb * 256;

  // --- A-gen ownership: row r (0..127), i-quarter q4 (16 i's per thread) ---
  const int r  = tid & 127;
  const int q4 = tid >> 7;           // 0..3
  const int wb0 = r * 128 + (((q4 * 2 + 0) ^ (r & 7)) * 16);
  const int wb1 = r * 128 + (((q4 * 2 + 1) ^ (r & 7)) * 16);

  // --- B staging: pre-swizzled per-lane global source, linear LDS dest ---
  const int cg = (lane & 7) ^ ((lane >> 3) & 7);
  const unsigned short* gb0 = Bt + (size_t)(bcol + w * 8 + (lane >> 3)) * KTOT + cg * 8;

  // --- fragment read geometry: 8 waves = 2M x 4N, wave tile 64x64 ---
  const int wr = w >> 2, wc = w & 3;
  const int l7 = lane & 7;
  const int rowA = wr * 64 + (lane & 15);
  const int rowB = wc * 64 + (lane & 15);

  // --- prologue: ALL x loads + trig(is=0); is=1 trig refreshed at p==16 ---
  float xf0[16], xf1[16], cth[16], sth[16];
  short8 xbf0a, xbf0b, xbf1a, xbf1b;   // raw x as bf16 (residual ring)
  const float* gx = x + (size_t)(brow + r) * INsz + ks * 128 + q4 * 16;
#pragma unroll
  for (int j = 0; j < 4; ++j) {
    f32x4 v0 = *reinterpret_cast<const f32x4*>(gx + j * 4);
    f32x4 v1 = *reinterpret_cast<const f32x4*>(gx + 64 + j * 4);
#pragma unroll
    for (int e = 0; e < 4; ++e) { xf0[j * 4 + e] = v0[e]; xf1[j * 4 + e] = v1[e]; }
  }
#pragma unroll
  for (int c = 0; c < 8; ++c) {
    xbf0a[c] = (short)f2bf(xf0[c]);     xbf0b[c] = (short)f2bf(xf0[c + 8]);
    xbf1a[c] = (short)f2bf(xf1[c]);     xbf1b[c] = (short)f2bf(xf1[c + 8]);
  }
  auto TRIG = [&](const float* xf) {
#pragma unroll
    for (int c = 0; c < 16; ++c) {
      float xc = fminf(fmaxf(xf[c], -1.0f), 1.0f);
      float wl = __builtin_fmaf(xc, 4.0e-9f, 1550.0e-9f);
      float hh = rc.K2 * xc * fastrcp(wl);
      float fr = fastfract(hh);
      cth[c] = cos2pi(fr);
      sth[c] = sin2pi(fr);
    }
  };
  TRIG(xf0);

  auto STAGE = [&](int p) {   // 4 gl_lds (4 x 64 rows) for B-tile of phase p
    const int is = (p >= 17) ? 1 : 0, n = p - 17 * is;
    const size_t koff = (size_t)(n * 512 + ks * 128 + is * 64);
    char* ldst = smB + (p % 3) * 32768 + w * 1024;
    const unsigned short* src = gb0 + koff;
#pragma unroll
    for (int iss = 0; iss < 4; ++iss)
      gl_lds16(src + (size_t)iss * 64 * KTOT, ldst + iss * 8192);
  };
  auto GENA = [&](int p) {    // generate A-tile of phase p into As[p&1]
    const int is = (p >= 17) ? 1 : 0, n = p - 17 * is;
    char* dst = smA + (p & 1) * 16384;
    if (n < NRING) {
      const float Crn = rc.Cr[n], Snn = rc.Snr[n];
#pragma unroll
      for (int g = 0; g < 2; ++g) {
        short8 wv;
#pragma unroll
        for (int e = 0; e < 8; ++e) {
          float cph = __builtin_fmaf(cth[g * 8 + e], Crn, sth[g * 8 + e] * Snn);
          wv[e] = (short)f2bf(fastrcp(cph + rc.SQ));
        }
        *reinterpret_cast<short8*>(dst + (g ? wb1 : wb0)) = wv;
      }
    } else {                  // residual ring: raw (unclipped) x, pre-packed
      *reinterpret_cast<short8*>(dst + wb0) = is ? xbf1a : xbf0a;
      *reinterpret_cast<short8*>(dst + wb1) = is ? xbf1b : xbf0b;
    }
  };

  f32x4 acc[4][4];
#pragma unroll
  for (int m = 0; m < 4; ++m)
#pragma unroll
    for (int q = 0; q < 4; ++q) acc[m][q] = (f32x4){0.f, 0.f, 0.f, 0.f};

  STAGE(0); STAGE(1);
  GENA(0);
  asm volatile("s_waitcnt vmcnt(4) lgkmcnt(0)" ::: "memory");
  __builtin_amdgcn_s_barrier();
  __builtin_amdgcn_sched_barrier(0);

#pragma unroll
  for (int p = 0; p < NPH; ++p) {
    const char* bA = smA + (p & 1) * 16384;
    const char* bB = smB + (p % 3) * 32768;
    short8 af[4], bfr[4];
    // ================= SUB 0 (kk=0) =================
    {
      const int oct = ((lane >> 4) ^ l7) * 16;
#pragma unroll
      for (int m = 0; m < 4; ++m)
        af[m] = *reinterpret_cast<const short8*>(bA + (rowA + m * 16) * 128 + oct);
#pragma unroll
      for (int q = 0; q < 4; ++q)
        bfr[q] = *reinterpret_cast<const short8*>(bB + (rowB + q * 16) * 128 + oct);
    }
    if (p + 2 < NPH) STAGE(p + 2);
    __builtin_amdgcn_s_barrier();
    asm volatile("s_waitcnt lgkmcnt(0)" ::: "memory");
    __builtin_amdgcn_sched_barrier(0);
    __builtin_amdgcn_s_setprio(1);
#pragma unroll
    for (int m = 0; m < 4; ++m)
#pragma unroll
      for (int q = 0; q < 4; ++q)
        acc[m][q] = __builtin_amdgcn_mfma_f32_16x16x32_bf16(af[m], bfr[q], acc[m][q], 0, 0, 0);
    __builtin_amdgcn_s_setprio(0);
    __builtin_amdgcn_s_barrier();
    // ================= SUB 1 (kk=1) =================
    {
      const int oct = (((lane >> 4) + 4) ^ l7) * 16;
#pragma unroll
      for (int m = 0; m < 4; ++m)
        af[m] = *reinterpret_cast<const short8*>(bA + (rowA + m * 16) * 128 + oct);
#pragma unroll
      for (int q = 0; q < 4; ++q)
        bfr[q] = *reinterpret_cast<const short8*>(bB + (rowB + q * 16) * 128 + oct);
    }
    if (p == 16) TRIG(xf1);           // refresh trig for is=1 (regs only)
    if (p + 1 < NPH) GENA(p + 1);
    __builtin_amdgcn_s_barrier();
    asm volatile("s_waitcnt lgkmcnt(0)" ::: "memory");
    __builtin_amdgcn_sched_barrier(0);
    __builtin_amdgcn_s_setprio(1);
#pragma unroll
    for (int m = 0; m < 4; ++m)
#pragma unroll
      for (int q = 0; q < 4; ++q)
        acc[m][q] = __builtin_amdgcn_mfma_f32_16x16x32_bf16(af[m], bfr[q], acc[m][q], 0, 0, 0);
    __builtin_amdgcn_s_setprio(0);
    if (p + 1 < NPH) {
      if (p + 2 < NPH) {
        asm volatile("s_waitcnt vmcnt(4)" ::: "memory");   // B(p+1) landed, B(p+2) in flight
      } else {
        asm volatile("s_waitcnt vmcnt(0)" ::: "memory");   // drain for last phase
      }
      __builtin_amdgcn_s_barrier();
      __builtin_amdgcn_sched_barrier(0);
    }
  }

  float* po = part + (size_t)ks * ((size_t)Bsz * OUTsz);
  const int r0 = brow + wr * 64 + ((lane >> 4) * 4);
  const int c0 = bcol + wc * 64 + (lane & 15);
#pragma unroll
  for (int m = 0; m < 4; ++m)
#pragma unroll
    for (int q = 0; q < 4; ++q)
#pragma unroll
      for (int e = 0; e < 4; ++e)
        po[(size_t)(r0 + m * 16 + e) * OUTsz + (c0 + q * 16)] = acc[m][q][e];
}

// ---- reduce 4 split-K partials + bias + kl ----
__global__ __launch_bounds__(256) void reduce_kernel(
    const f32x4* __restrict__ part, const f32x4* __restrict__ bias,
    float* __restrict__ out) {
  const size_t idx = (size_t)blockIdx.x * 256 + threadIdx.x;
  const size_t stride = (size_t)Bsz * OUTsz / 4;
  f32x4 v = part[idx] + part[idx + stride] + part[idx + 2 * stride] + part[idx + 3 * stride];
  v = v + bias[idx & 127];
  reinterpret_cast<f32x4*>(out)[idx] = v;
  if (idx == 0) out[(size_t)Bsz * OUTsz] = 0.0f;   // kl
}

extern "C" void kernel_launch(void* const* d_in, const int* in_sizes, int n_in,
                              void* d_out, int out_size, void* d_ws, size_t ws_size,
                              hipStream_t stream) {
  const float* x      = (const float*)d_in[0];
  const float* coeffs = (const float*)d_in[1];
  const float* bw     = (const float*)d_in[2];
  float* out = (float*)d_out;

  unsigned short* Bt = (unsigned short*)d_ws;                              // 8,912,896 B
  float* part = (float*)((char*)d_ws + (size_t)OUTsz * KTOT * 2);          // 33,554,432 B
  float* bias = (float*)((char*)d_ws + (size_t)OUTsz * KTOT * 2
                                     + (size_t)SPLITK * Bsz * OUTsz * 4);  // 2048 B

  RC rc;
  float PQ;
  {
    const double PI  = 3.14159265358979323846;
    const double Lc  = 2.0 * PI * 30.0e-6;
    const double WL0 = 1550.0e-9;
    const double NG  = 4.2;
    const double Aamp = pow(10.0, -3.0 * (Lc * 100.0) / 20.0);
    const double Rt2  = 0.8;
    const double Rt   = sqrt(Rt2);
    for (int rr = 0; rr < NRING; ++rr) {
      double off  = -PI + rr * (2.0 * PI / 15.0);
      double neff = 2.34 + off * WL0 / (2.0 * PI * Lc);
      double rev0 = (Lc / WL0) * neff;
      rc.Cr[rr]  = (float)cos(2.0 * PI * rev0);
      rc.Snr[rr] = (float)(-sin(2.0 * PI * rev0));
    }
    const double qn = -2.0 * Rt * Aamp;
    const double s  = 1.0 + Rt2 * Aamp * Aamp;
    const double P  = -(1.0 - Aamp * Aamp) * (1.0 - Rt2);
    rc.K2 = (float)(-4.0e-9 * Lc * NG / WL0);
    rc.SQ = (float)(s / qn);
    rc.pad0 = rc.pad1 = 0.f;
    PQ = (float)(P / qn);
  }

  hipFuncSetAttribute(reinterpret_cast<const void*>(gemm_fused_kernel),
                      hipFuncAttributeMaxDynamicSharedMemorySize, 131072);

  hipLaunchKernelGGL(pack_b_kernel, dim3(OUTsz), dim3(512), 0, stream,
                     coeffs, bw, Bt, bias, PQ);
  hipLaunchKernelGGL(gemm_fused_kernel, dim3(256), dim3(512), 131072, stream,
                     x, Bt, part, rc);
  hipLaunchKernelGGL(reduce_kernel, dim3((Bsz * OUTsz / 4) / 256), dim3(256), 0, stream,
                     (const f32x4*)part, (const f32x4*)bias, out);
}